// Round 5
// baseline (475.434 us; speedup 1.0000x reference)
//
#include <hip/hip_runtime.h>

#define T_TOK 8192
#define H_DIM 4096
#define O_DIM 4096
#define R_RANK 16
#define N_AD 8

#define TB_S 32      // tokens per shrink block
#define HC 128       // h-chunk staged per iteration
#define HSPLIT 4     // h-range splits (grid.y)
#define HRANGE (H_DIM / HSPLIT)   // 1024 h per block
#define TB_E 32      // tokens per expand block
#define OB 1024      // output columns per expand block

// ---------------- sort: bucket tokens by adapter (ballot-based) ----------------
__global__ void hist_kernel(const int* __restrict__ idx, int* __restrict__ cnt) {
    const int t = blockIdx.x * 256 + threadIdx.x;   // grid 32x256 = 8192 exactly
    const int a = idx[t];
    const int lane = threadIdx.x & 63;
    #pragma unroll
    for (int k = 0; k < N_AD; ++k) {
        unsigned long long m = __ballot(a == k);
        if (lane == 0 && m) atomicAdd(&cnt[k], (int)__popcll(m));
    }
}

__global__ void scan_kernel(const int* __restrict__ cnt, int* __restrict__ base,
                            int* __restrict__ cur) {
    int s = 0;
    #pragma unroll
    for (int a = 0; a < N_AD; ++a) { base[a] = s; cur[a] = s; s += cnt[a]; }
    base[N_AD] = s;
}

__global__ void scatter_kernel(const int* __restrict__ idx, int* __restrict__ cur,
                               int* __restrict__ list) {
    const int t = blockIdx.x * 256 + threadIdx.x;
    const int a = idx[t];
    const int lane = threadIdx.x & 63;
    const unsigned long long lt_mask = (1ull << lane) - 1ull;
    #pragma unroll
    for (int k = 0; k < N_AD; ++k) {
        unsigned long long m = __ballot(a == k);
        if (m) {
            int s = 0;
            if (lane == 0) s = atomicAdd(&cur[k], (int)__popcll(m));
            s = __shfl(s, 0);
            if (a == k) list[s + (int)__popcll(m & lt_mask)] = t;
        }
    }
}

// ---------------- shrink: V4[split][t][16] = x[t][hrange] @ A[a][hrange] ----------------
// grid: (T/32, HSPLIT, N_AD), 256 threads.
// thread org: hs = tid>>3 (32 h-segments), tg = tid&7 (8 groups of 4 tokens).
__global__ __launch_bounds__(256, 4) void shrink_kernel(
    const float* __restrict__ x, const float* __restrict__ lora_a,
    const int* __restrict__ list, const int* __restrict__ base,
    float* __restrict__ V4) {
    const int a = blockIdx.z;
    const int s0 = base[a], s1 = base[a + 1];
    const int start = s0 + blockIdx.x * TB_S;
    if (start >= s1) return;
    const int nt = min(TB_S, s1 - start);

    __shared__ float x_t[TB_S][HC + 1];     // 16.5 KB
    __shared__ float a_t[HC][20];           // 10 KB, stride-20: conflict-free b128
    __shared__ float red2[4][8][4][16];     // 8 KB cross-wave reduction
    __shared__ int toks[TB_S];

    const int tid = threadIdx.x;
    const int hs = tid >> 3;
    const int tg = tid & 7;
    const int hb = blockIdx.y * HRANGE;

    if (tid < TB_S) toks[tid] = (tid < nt) ? list[start + tid] : -1;
    __syncthreads();

    float vacc[4][16];
    #pragma unroll
    for (int i = 0; i < 4; ++i)
        #pragma unroll
        for (int r = 0; r < 16; ++r) vacc[i][r] = 0.f;

    const float* Abase = lora_a + (size_t)a * H_DIM * R_RANK;

    for (int c = 0; c < HRANGE / HC; ++c) {
        const int h0 = hb + c * HC;
        // stage x tile: 32 rows x 128 cols (1024 float4, 4 passes)
        #pragma unroll
        for (int k = 0; k < 4; ++k) {
            int flat = k * 256 + tid;
            int row = flat >> 5, col4 = flat & 31;
            int t = toks[row];
            float4 vx = make_float4(0.f, 0.f, 0.f, 0.f);
            if (t >= 0) vx = *(const float4*)&x[(size_t)t * H_DIM + h0 + (col4 << 2)];
            float* dst = &x_t[row][col4 << 2];
            dst[0] = vx.x; dst[1] = vx.y; dst[2] = vx.z; dst[3] = vx.w;
        }
        // stage A chunk: 128 h x 16 r (512 float4, 2 passes)
        #pragma unroll
        for (int k = 0; k < 2; ++k) {
            int flat = k * 256 + tid;
            int h = flat >> 2, q = flat & 3;
            *(float4*)&a_t[h][q << 2] =
                *(const float4*)&Abase[(size_t)(h0 + h) * R_RANK + (q << 2)];
        }
        __syncthreads();

        #pragma unroll
        for (int hh = 0; hh < HC / 32; ++hh) {
            const int h = (hh << 5) + hs;
            const float4 a0 = *(const float4*)&a_t[h][0];
            const float4 a1 = *(const float4*)&a_t[h][4];
            const float4 a2 = *(const float4*)&a_t[h][8];
            const float4 a3 = *(const float4*)&a_t[h][12];
            #pragma unroll
            for (int i = 0; i < 4; ++i) {
                const float xv = x_t[(tg << 2) + i][h];
                vacc[i][0]  += xv * a0.x; vacc[i][1]  += xv * a0.y;
                vacc[i][2]  += xv * a0.z; vacc[i][3]  += xv * a0.w;
                vacc[i][4]  += xv * a1.x; vacc[i][5]  += xv * a1.y;
                vacc[i][6]  += xv * a1.z; vacc[i][7]  += xv * a1.w;
                vacc[i][8]  += xv * a2.x; vacc[i][9]  += xv * a2.y;
                vacc[i][10] += xv * a2.z; vacc[i][11] += xv * a2.w;
                vacc[i][12] += xv * a3.x; vacc[i][13] += xv * a3.y;
                vacc[i][14] += xv * a3.z; vacc[i][15] += xv * a3.w;
            }
        }
        __syncthreads();
    }

    // reduce over 32 h-segments: shuffle (lane bits 3..5), then LDS over 4 waves
    #pragma unroll
    for (int i = 0; i < 4; ++i)
        #pragma unroll
        for (int r = 0; r < 16; ++r) {
            float f = vacc[i][r];
            f += __shfl_xor(f, 8);
            f += __shfl_xor(f, 16);
            f += __shfl_xor(f, 32);
            vacc[i][r] = f;
        }
    const int lane = tid & 63, w = tid >> 6;
    if ((lane >> 3) == 0) {
        #pragma unroll
        for (int i = 0; i < 4; ++i)
            #pragma unroll
            for (int q = 0; q < 4; ++q)
                *(float4*)&red2[w][tg][i][q << 2] =
                    make_float4(vacc[i][(q << 2)], vacc[i][(q << 2) + 1],
                                vacc[i][(q << 2) + 2], vacc[i][(q << 2) + 3]);
    }
    __syncthreads();
    if (tid < 128) {
        const int tl = tid >> 2, q = tid & 3;
        const int tg2 = tl >> 2, i2 = tl & 3;
        float4 s = make_float4(0.f, 0.f, 0.f, 0.f);
        #pragma unroll
        for (int w2 = 0; w2 < 4; ++w2) {
            const float4 p = *(const float4*)&red2[w2][tg2][i2][q << 2];
            s.x += p.x; s.y += p.y; s.z += p.z; s.w += p.w;
        }
        const int t = toks[tl];
        if (t >= 0)
            *(float4*)&V4[((size_t)blockIdx.y * T_TOK + t) * R_RANK + (q << 2)] = s;
    }
}

// ---------------- expand: out[t] = result[t] + (sum_split V4) @ B[a] ----------------
// grid: (T/32, O/OB, N_AD), 256 threads; thread owns 1 float4 of o, B[16] in regs.
__global__ __launch_bounds__(256, 4) void expand_kernel(
    const float* __restrict__ result, const float* __restrict__ lora_b,
    const float* __restrict__ V4, const int* __restrict__ list,
    const int* __restrict__ base, float* __restrict__ out) {
    const int a = blockIdx.z;
    const int s0 = base[a], s1 = base[a + 1];
    const int start = s0 + blockIdx.x * TB_E;
    if (start >= s1) return;
    const int nt = min(TB_E, s1 - start);
    const int tid = threadIdx.x;

    __shared__ float v_lds[TB_E][16];
    __shared__ int toks[TB_E];
    if (tid < TB_E) toks[tid] = (tid < nt) ? list[start + tid] : -1;
    __syncthreads();
    if (tid < 128) {
        const int tl = tid >> 2, q = tid & 3;
        const int t = toks[tl];
        float4 s = make_float4(0.f, 0.f, 0.f, 0.f);
        if (t >= 0) {
            #pragma unroll
            for (int sp = 0; sp < HSPLIT; ++sp) {
                const float4 p = *(const float4*)
                    &V4[((size_t)sp * T_TOK + t) * R_RANK + (q << 2)];
                s.x += p.x; s.y += p.y; s.z += p.z; s.w += p.w;
            }
        }
        *(float4*)&v_lds[tl][q << 2] = s;
    }

    const size_t o0 = (size_t)blockIdx.y * OB + ((size_t)tid << 2);
    const float* Bb = lora_b + (size_t)a * R_RANK * O_DIM + o0;
    float4 b[16];
    #pragma unroll
    for (int r = 0; r < 16; ++r) b[r] = *(const float4*)&Bb[(size_t)r * O_DIM];
    __syncthreads();

    int tl = 0;
    for (; tl + 2 <= nt; tl += 2) {
        const int t0 = toks[tl], t1 = toks[tl + 1];
        float4 acc0 = *(const float4*)&result[(size_t)t0 * O_DIM + o0];
        float4 acc1 = *(const float4*)&result[(size_t)t1 * O_DIM + o0];
        #pragma unroll
        for (int r = 0; r < 16; ++r) {
            const float v0 = v_lds[tl][r], v1 = v_lds[tl + 1][r];
            acc0.x += v0 * b[r].x; acc0.y += v0 * b[r].y;
            acc0.z += v0 * b[r].z; acc0.w += v0 * b[r].w;
            acc1.x += v1 * b[r].x; acc1.y += v1 * b[r].y;
            acc1.z += v1 * b[r].z; acc1.w += v1 * b[r].w;
        }
        *(float4*)&out[(size_t)t0 * O_DIM + o0] = acc0;
        *(float4*)&out[(size_t)t1 * O_DIM + o0] = acc1;
    }
    if (tl < nt) {
        const int t0 = toks[tl];
        float4 acc0 = *(const float4*)&result[(size_t)t0 * O_DIM + o0];
        #pragma unroll
        for (int r = 0; r < 16; ++r) {
            const float v0 = v_lds[tl][r];
            acc0.x += v0 * b[r].x; acc0.y += v0 * b[r].y;
            acc0.z += v0 * b[r].z; acc0.w += v0 * b[r].w;
        }
        *(float4*)&out[(size_t)t0 * O_DIM + o0] = acc0;
    }
}

extern "C" void kernel_launch(void* const* d_in, const int* in_sizes, int n_in,
                              void* d_out, int out_size, void* d_ws, size_t ws_size,
                              hipStream_t stream) {
    const float* result = (const float*)d_in[0];
    const float* x      = (const float*)d_in[1];
    const float* lora_a = (const float*)d_in[2];
    const float* lora_b = (const float*)d_in[3];
    const int*   aidx   = (const int*)d_in[4];
    float* out = (float*)d_out;

    char* ws = (char*)d_ws;
    float* V4  = (float*)ws;                                     // 4*T*16*4 = 2 MB
    size_t off = (size_t)HSPLIT * T_TOK * R_RANK * 4;
    int* list  = (int*)(ws + off);   off += (size_t)T_TOK * 4;   // 32 KB
    int* base  = (int*)(ws + off);   off += 16 * 4;
    int* cnt   = (int*)(ws + off);   off += 16 * 4;
    int* cur   = (int*)(ws + off);

    hipMemsetAsync(cnt, 0, N_AD * sizeof(int), stream);
    hist_kernel<<<T_TOK / 256, 256, 0, stream>>>(aidx, cnt);
    scan_kernel<<<1, 1, 0, stream>>>(cnt, base, cur);
    scatter_kernel<<<T_TOK / 256, 256, 0, stream>>>(aidx, cur, list);
    shrink_kernel<<<dim3(T_TOK / TB_S, HSPLIT, N_AD), 256, 0, stream>>>(
        x, lora_a, list, base, V4);
    expand_kernel<<<dim3(T_TOK / TB_E, O_DIM / OB, N_AD), 256, 0, stream>>>(
        result, lora_b, V4, list, base, out);
}

// Round 6
// 462.419 us; speedup vs baseline: 1.0281x; 1.0281x over previous
//
#include <hip/hip_runtime.h>

#define T_TOK 8192
#define H_DIM 4096
#define O_DIM 4096
#define R_RANK 16
#define N_AD 8

#define TB_S 32      // tokens per tile (shrink & expand)
#define HC 128       // h-chunk staged per iteration
#define HSPLIT 4     // h-range splits (grid.y of shrink)
#define HRANGE (H_DIM / HSPLIT)   // 1024 h per block
#define OB 1024      // output columns per expand block
#define NTILE_MAX (T_TOK / TB_S + N_AD)   // 264: worst-case tile count

// ---------------- sort: bucket tokens by adapter (ballot-based) ----------------
__global__ void hist_kernel(const int* __restrict__ idx, int* __restrict__ cnt) {
    const int t = blockIdx.x * 256 + threadIdx.x;   // grid 32x256 = 8192 exactly
    const int a = idx[t];
    const int lane = threadIdx.x & 63;
    #pragma unroll
    for (int k = 0; k < N_AD; ++k) {
        unsigned long long m = __ballot(a == k);
        if (lane == 0 && m) atomicAdd(&cnt[k], (int)__popcll(m));
    }
}

__global__ void scan_kernel(const int* __restrict__ cnt, int* __restrict__ base,
                            int* __restrict__ cur, int* __restrict__ tbase) {
    int s = 0, tt = 0;
    #pragma unroll
    for (int a = 0; a < N_AD; ++a) {
        base[a] = s; cur[a] = s; tbase[a] = tt;
        s += cnt[a]; tt += (cnt[a] + TB_S - 1) / TB_S;
    }
    base[N_AD] = s; tbase[N_AD] = tt;
}

__global__ void scatter_kernel(const int* __restrict__ idx, int* __restrict__ cur,
                               int* __restrict__ list) {
    const int t = blockIdx.x * 256 + threadIdx.x;
    const int a = idx[t];
    const int lane = threadIdx.x & 63;
    const unsigned long long lt_mask = (1ull << lane) - 1ull;
    #pragma unroll
    for (int k = 0; k < N_AD; ++k) {
        unsigned long long m = __ballot(a == k);
        if (m) {
            int s = 0;
            if (lane == 0) s = atomicAdd(&cur[k], (int)__popcll(m));
            s = __shfl(s, 0);
            if (a == k) list[s + (int)__popcll(m & lt_mask)] = t;
        }
    }
}

// tile search: a = largest k with tbase[k] <= b  (requires b < tbase[N_AD])
__device__ __forceinline__ int find_adapter(const int* stb, int b) {
    int a = 0;
    #pragma unroll
    for (int k = 1; k < N_AD; ++k) if (b >= stb[k]) a = k;
    return a;
}

// ---------------- shrink: V4[split][t][16] = x[t][hrange] @ A[a][hrange] ----------------
// grid: (NTILE_MAX, HSPLIT), 256 threads. Dense tile ids -> even CU spread.
__global__ __launch_bounds__(256, 4) void shrink_kernel(
    const float* __restrict__ x, const float* __restrict__ lora_a,
    const int* __restrict__ list, const int* __restrict__ base,
    const int* __restrict__ tbase, float* __restrict__ V4) {
    __shared__ int stb[N_AD + 1];
    __shared__ float x_t[TB_S][HC + 1];     // 16.5 KB
    __shared__ float a_t[HC][20];           // 10 KB, stride-20: conflict-free b128
    __shared__ float red2[4][8][4][16];     // 8 KB cross-wave reduction
    __shared__ int toks[TB_S];

    const int tid = threadIdx.x;
    if (tid <= N_AD) stb[tid] = tbase[tid];
    __syncthreads();

    const int b = blockIdx.x;
    if (b >= stb[N_AD]) return;
    const int a = find_adapter(stb, b);
    const int s0 = base[a], s1 = base[a + 1];
    const int start = s0 + (b - stb[a]) * TB_S;
    const int nt = min(TB_S, s1 - start);

    const int hs = tid >> 3;
    const int tg = tid & 7;
    const int hb = blockIdx.y * HRANGE;

    if (tid < TB_S) toks[tid] = (tid < nt) ? list[start + tid] : -1;
    __syncthreads();

    float vacc[4][16];
    #pragma unroll
    for (int i = 0; i < 4; ++i)
        #pragma unroll
        for (int r = 0; r < 16; ++r) vacc[i][r] = 0.f;

    const float* Abase = lora_a + (size_t)a * H_DIM * R_RANK;

    for (int c = 0; c < HRANGE / HC; ++c) {
        const int h0 = hb + c * HC;
        // stage x tile: 32 rows x 128 cols (1024 float4, 4 passes)
        #pragma unroll
        for (int k = 0; k < 4; ++k) {
            int flat = k * 256 + tid;
            int row = flat >> 5, col4 = flat & 31;
            int t = toks[row];
            float4 vx = make_float4(0.f, 0.f, 0.f, 0.f);
            if (t >= 0) vx = *(const float4*)&x[(size_t)t * H_DIM + h0 + (col4 << 2)];
            float* dst = &x_t[row][col4 << 2];
            dst[0] = vx.x; dst[1] = vx.y; dst[2] = vx.z; dst[3] = vx.w;
        }
        // stage A chunk: 128 h x 16 r (512 float4, 2 passes)
        #pragma unroll
        for (int k = 0; k < 2; ++k) {
            int flat = k * 256 + tid;
            int h = flat >> 2, q = flat & 3;
            *(float4*)&a_t[h][q << 2] =
                *(const float4*)&Abase[(size_t)(h0 + h) * R_RANK + (q << 2)];
        }
        __syncthreads();

        #pragma unroll
        for (int hh = 0; hh < HC / 32; ++hh) {
            const int h = (hh << 5) + hs;
            const float4 a0 = *(const float4*)&a_t[h][0];
            const float4 a1 = *(const float4*)&a_t[h][4];
            const float4 a2 = *(const float4*)&a_t[h][8];
            const float4 a3 = *(const float4*)&a_t[h][12];
            #pragma unroll
            for (int i = 0; i < 4; ++i) {
                const float xv = x_t[(tg << 2) + i][h];
                vacc[i][0]  += xv * a0.x; vacc[i][1]  += xv * a0.y;
                vacc[i][2]  += xv * a0.z; vacc[i][3]  += xv * a0.w;
                vacc[i][4]  += xv * a1.x; vacc[i][5]  += xv * a1.y;
                vacc[i][6]  += xv * a1.z; vacc[i][7]  += xv * a1.w;
                vacc[i][8]  += xv * a2.x; vacc[i][9]  += xv * a2.y;
                vacc[i][10] += xv * a2.z; vacc[i][11] += xv * a2.w;
                vacc[i][12] += xv * a3.x; vacc[i][13] += xv * a3.y;
                vacc[i][14] += xv * a3.z; vacc[i][15] += xv * a3.w;
            }
        }
        __syncthreads();
    }

    // reduce over 32 h-segments: shuffle (lane bits 3..5), then LDS over 4 waves
    #pragma unroll
    for (int i = 0; i < 4; ++i)
        #pragma unroll
        for (int r = 0; r < 16; ++r) {
            float f = vacc[i][r];
            f += __shfl_xor(f, 8);
            f += __shfl_xor(f, 16);
            f += __shfl_xor(f, 32);
            vacc[i][r] = f;
        }
    const int lane = tid & 63, w = tid >> 6;
    if ((lane >> 3) == 0) {
        #pragma unroll
        for (int i = 0; i < 4; ++i)
            #pragma unroll
            for (int q = 0; q < 4; ++q)
                *(float4*)&red2[w][tg][i][q << 2] =
                    make_float4(vacc[i][(q << 2)], vacc[i][(q << 2) + 1],
                                vacc[i][(q << 2) + 2], vacc[i][(q << 2) + 3]);
    }
    __syncthreads();
    if (tid < 128) {
        const int tl = tid >> 2, q = tid & 3;
        const int tg2 = tl >> 2, i2 = tl & 3;
        float4 s = make_float4(0.f, 0.f, 0.f, 0.f);
        #pragma unroll
        for (int w2 = 0; w2 < 4; ++w2) {
            const float4 p = *(const float4*)&red2[w2][tg2][i2][q << 2];
            s.x += p.x; s.y += p.y; s.z += p.z; s.w += p.w;
        }
        const int t = toks[tl];
        if (t >= 0)
            *(float4*)&V4[((size_t)blockIdx.y * T_TOK + t) * R_RANK + (q << 2)] = s;
    }
}

// ---------------- expand: out[t] = result[t] + (sum_split V4) @ B[a] ----------------
// grid: (NTILE_MAX, O/OB), 256 threads; thread owns 1 float4 of o, B[16] in regs.
__global__ __launch_bounds__(256, 4) void expand_kernel(
    const float* __restrict__ result, const float* __restrict__ lora_b,
    const float* __restrict__ V4, const int* __restrict__ list,
    const int* __restrict__ base, const int* __restrict__ tbase,
    float* __restrict__ out) {
    __shared__ int stb[N_AD + 1];
    __shared__ float v_lds[TB_S][16];
    __shared__ int toks[TB_S];

    const int tid = threadIdx.x;
    if (tid <= N_AD) stb[tid] = tbase[tid];
    __syncthreads();

    const int b = blockIdx.x;
    if (b >= stb[N_AD]) return;
    const int a = find_adapter(stb, b);
    const int s0 = base[a], s1 = base[a + 1];
    const int start = s0 + (b - stb[a]) * TB_S;
    const int nt = min(TB_S, s1 - start);

    if (tid < TB_S) toks[tid] = (tid < nt) ? list[start + tid] : -1;
    __syncthreads();
    if (tid < 128) {
        const int tl = tid >> 2, q = tid & 3;
        const int t = toks[tl];
        float4 s = make_float4(0.f, 0.f, 0.f, 0.f);
        if (t >= 0) {
            #pragma unroll
            for (int sp = 0; sp < HSPLIT; ++sp) {
                const float4 p = *(const float4*)
                    &V4[((size_t)sp * T_TOK + t) * R_RANK + (q << 2)];
                s.x += p.x; s.y += p.y; s.z += p.z; s.w += p.w;
            }
        }
        *(float4*)&v_lds[tl][q << 2] = s;
    }

    const size_t o0 = (size_t)blockIdx.y * OB + ((size_t)tid << 2);
    const float* Bb = lora_b + (size_t)a * R_RANK * O_DIM + o0;
    float4 bb[16];
    #pragma unroll
    for (int r = 0; r < 16; ++r) bb[r] = *(const float4*)&Bb[(size_t)r * O_DIM];
    __syncthreads();

    int tl = 0;
    for (; tl + 2 <= nt; tl += 2) {
        const int t0 = toks[tl], t1 = toks[tl + 1];
        float4 acc0 = *(const float4*)&result[(size_t)t0 * O_DIM + o0];
        float4 acc1 = *(const float4*)&result[(size_t)t1 * O_DIM + o0];
        #pragma unroll
        for (int r = 0; r < 16; ++r) {
            const float v0 = v_lds[tl][r], v1 = v_lds[tl + 1][r];
            acc0.x += v0 * bb[r].x; acc0.y += v0 * bb[r].y;
            acc0.z += v0 * bb[r].z; acc0.w += v0 * bb[r].w;
            acc1.x += v1 * bb[r].x; acc1.y += v1 * bb[r].y;
            acc1.z += v1 * bb[r].z; acc1.w += v1 * bb[r].w;
        }
        *(float4*)&out[(size_t)t0 * O_DIM + o0] = acc0;
        *(float4*)&out[(size_t)t1 * O_DIM + o0] = acc1;
    }
    if (tl < nt) {
        const int t0 = toks[tl];
        float4 acc0 = *(const float4*)&result[(size_t)t0 * O_DIM + o0];
        #pragma unroll
        for (int r = 0; r < 16; ++r) {
            const float v0 = v_lds[tl][r];
            acc0.x += v0 * bb[r].x; acc0.y += v0 * bb[r].y;
            acc0.z += v0 * bb[r].z; acc0.w += v0 * bb[r].w;
        }
        *(float4*)&out[(size_t)t0 * O_DIM + o0] = acc0;
    }
}

extern "C" void kernel_launch(void* const* d_in, const int* in_sizes, int n_in,
                              void* d_out, int out_size, void* d_ws, size_t ws_size,
                              hipStream_t stream) {
    const float* result = (const float*)d_in[0];
    const float* x      = (const float*)d_in[1];
    const float* lora_a = (const float*)d_in[2];
    const float* lora_b = (const float*)d_in[3];
    const int*   aidx   = (const int*)d_in[4];
    float* out = (float*)d_out;

    char* ws = (char*)d_ws;
    float* V4   = (float*)ws;                                    // 4*T*16*4 = 2 MB
    size_t off  = (size_t)HSPLIT * T_TOK * R_RANK * 4;
    int* list   = (int*)(ws + off);   off += (size_t)T_TOK * 4;  // 32 KB
    int* base   = (int*)(ws + off);   off += 16 * 4;
    int* cnt    = (int*)(ws + off);   off += 16 * 4;
    int* cur    = (int*)(ws + off);   off += 16 * 4;
    int* tbase  = (int*)(ws + off);

    hipMemsetAsync(cnt, 0, N_AD * sizeof(int), stream);
    hist_kernel<<<T_TOK / 256, 256, 0, stream>>>(aidx, cnt);
    scan_kernel<<<1, 1, 0, stream>>>(cnt, base, cur, tbase);
    scatter_kernel<<<T_TOK / 256, 256, 0, stream>>>(aidx, cur, list);
    shrink_kernel<<<dim3(NTILE_MAX, HSPLIT), 256, 0, stream>>>(
        x, lora_a, list, base, tbase, V4);
    expand_kernel<<<dim3(NTILE_MAX, O_DIM / OB), 256, 0, stream>>>(
        result, lora_b, V4, list, base, tbase, out);
}